// Round 6
// baseline (192.607 us; speedup 1.0000x reference)
//
#include <hip/hip_runtime.h>
#include <stdint.h>

// SSIM loss — fused separable box filter. R11 resubmit (two consecutive
// GPUAcquisitionTimeouts; kernel never ran). Traffic-first redesign.
// R10 post-mortem: occupancy x2 (16 waves/CU) made it SLOWER (74->85us,
// VALUBusy 38->32) because SH=8 raised issued-vmem per output (27 row-reads
// per 8 rows = 3.38x vs R8's 2.69x). Warm-L3 replays run identical to cold
// -> bound by the per-CU issued-request path, NOT HBM and NOT waves.
// Lever: cut issued bytes. R8 issued 344 MB = 2.69x the 128 MB minimum
// (vertical-halo warmup + global re-read of every subtract row).
//
// R11: one wave owns a SH=64-row x 512-col band with a 13-slot LDS row ring
// (slot = x row 2KB + y row 2KB). Each input row is DMA'd ONCE and lives in
// the ring 11 iterations until it becomes the subtract row (12 live rows +
// 1 prefetch slot = 13). Issued vmem = 512 blocks x 75 rows x 4KB = 154 MB
// (1.17x minimum, 2.24x less than R8). LDS 53KB/wave -> 3 blocks/CU by LDS,
// 2 resident at grid 512: low occupancy BY DESIGN — R10 proved waves are
// not the constraint; per-row compute (~900cyc) covers the 1-iteration DMA
// prefetch distance exactly as in the verified R8 structure (the implicit
// vmcnt(0) at the consuming ds_read only ever sees a 1-iteration-old DMA).
//
// Ring slot map (q = input row, band base r0): slot(q) = (q - r0 + 5) mod 13.
// Step r: add row r+5 (slot sAdd), sub row r-6 (slot sSub, gated: only rows
// previously added; garbage slots never read), prefetch row r+6 (slot sPre =
// slot of dead row r-7). Cursors advance by 1 mod 13 each step.
// Horizontal 11-col window: 5-float halo per side via __shfl (unchanged).

#define IMG_H 512
#define IMG_W 512
#define N_IMG 64
#define RAD   5
#define SH    64
#define NBANDG 8
#define NBLOCKS (N_IMG * NBANDG)   // 512
#define NSLOT 13

#define C1_SSIM 1.0e-4f
#define C2_SSIM 9.0e-4f

#define SLOT_BYTES 4096            // x row (2048 B) + y row (2048 B)

typedef __attribute__((address_space(3))) uint32_t lds_u32_t;
typedef const __attribute__((address_space(1))) uint32_t glb_u32_t;

__device__ __forceinline__ void dma16(void* lds, const void* g) {
    // 64 lanes x 16 B: LDS dest = wave-uniform base + lane*16 (m104/m108)
    __builtin_amdgcn_global_load_lds((glb_u32_t*)g, (lds_u32_t*)lds, 16, 0, 0);
}

__global__ __launch_bounds__(64) void ssim_fused(const float* __restrict__ x,
                                                 const float* __restrict__ y,
                                                 float* __restrict__ part)
{
    __shared__ __align__(16) char ring[NSLOT][SLOT_BYTES];   // 53,248 B

    const int tx  = threadIdx.x;                // 0..63, single wave

    // XCD-aware bijective swizzle (512%8==0): XCD k owns images [8k,8k+8).
    const int wid = (blockIdx.x & 7) * (NBLOCKS / 8) + (blockIdx.x >> 3);
    const int img = wid >> 3;                   // / NBANDG
    const int bg  = wid & (NBANDG - 1);
    const int r0  = bg * SH;
    // lane owns cols tx*8 .. tx*8+7 (implicit: all LDS reads at tx*32)

    const float* __restrict__ xi = x + (size_t)img * (IMG_H * IMG_W);
    const float* __restrict__ yi = y + (size_t)img * (IMG_H * IMG_W);

    // DMA one (x,y) row pair into ring slot. Clamped rows load valid (finite)
    // data; their contribution is zeroed at accumulate time.
    auto dma_row = [&](int slot, int ri) {
        int rc = ri < 0 ? 0 : (ri > IMG_H - 1 ? IMG_H - 1 : ri);
        char* s = &ring[slot][0];
        const char* xg = (const char*)(xi + (size_t)rc * IMG_W) + tx * 16;
        const char* yg = (const char*)(yi + (size_t)rc * IMG_W) + tx * 16;
        dma16(s,        xg);
        dma16(s + 1024, xg + 1024);
        dma16(s + 2048, yg);
        dma16(s + 3072, yg + 1024);
    };

    float Vx[8], Vy[8], Vss[8], Vxy[8];
#pragma unroll
    for (int j = 0; j < 8; ++j) { Vx[j] = 0.f; Vy[j] = 0.f; Vss[j] = 0.f; Vxy[j] = 0.f; }

    // add f * (row moments) from a ring slot; f = 0/1 edge scale
    auto accum_add = [&](const char* s, float f) {
        const float4* xr = (const float4*)(s + (size_t)tx * 32);
        const float4* yr = (const float4*)(s + 2048 + (size_t)tx * 32);
        float4 x0 = xr[0], x1 = xr[1];
        float4 y0 = yr[0], y1 = yr[1];
        float xs[8] = {x0.x, x0.y, x0.z, x0.w, x1.x, x1.y, x1.z, x1.w};
        float ys[8] = {y0.x, y0.y, y0.z, y0.w, y1.x, y1.y, y1.z, y1.w};
#pragma unroll
        for (int j = 0; j < 8; ++j) {
            float fx = f * xs[j];
            float fy = f * ys[j];
            Vx[j] += fx;
            Vy[j] += fy;
            Vss[j] = fmaf(fx, xs[j], Vss[j]);
            Vss[j] = fmaf(fy, ys[j], Vss[j]);
            Vxy[j] = fmaf(fx, ys[j], Vxy[j]);
        }
    };

    // subtract row moments from a ring slot (only called for rows that were
    // previously added with f=1, so no scale needed)
    auto accum_sub = [&](const char* s) {
        const float4* xr = (const float4*)(s + (size_t)tx * 32);
        const float4* yr = (const float4*)(s + 2048 + (size_t)tx * 32);
        float4 x0 = xr[0], x1 = xr[1];
        float4 y0 = yr[0], y1 = yr[1];
        float xs[8] = {x0.x, x0.y, x0.z, x0.w, x1.x, x1.y, x1.z, x1.w};
        float ys[8] = {y0.x, y0.y, y0.z, y0.w, y1.x, y1.y, y1.z, y1.w};
#pragma unroll
        for (int j = 0; j < 8; ++j) {
            Vx[j]  -= xs[j];
            Vy[j]  -= ys[j];
            Vss[j] = fmaf(-xs[j], xs[j], Vss[j]);
            Vss[j] = fmaf(-ys[j], ys[j], Vss[j]);
            Vxy[j] = fmaf(-xs[j], ys[j], Vxy[j]);
        }
    };

    // 11-tap sliding horizontal sums; halo via lane+-1 shuffles
    auto hsum = [&](const float (&V)[8], float (&S)[8]) {
        float w[18];
#pragma unroll
        for (int k = 0; k < 5; ++k) {
            float l = __shfl_up(V[3 + k], 1, 64);
            w[k] = (tx == 0) ? 0.f : l;
        }
#pragma unroll
        for (int j = 0; j < 8; ++j) w[5 + j] = V[j];
#pragma unroll
        for (int k = 0; k < 5; ++k) {
            float r = __shfl_down(V[k], 1, 64);
            w[13 + k] = (tx == 63) ? 0.f : r;
        }
        float s = 0.f;
#pragma unroll
        for (int t = 0; t < 11; ++t) s += w[t];
        S[0] = s;
#pragma unroll
        for (int j = 1; j < 8; ++j) { s += w[j + 10] - w[j - 1]; S[j] = s; }
    };

    // ---- warm-up: fill slots 0..10 with rows r0-5 .. r0+5 (one DMA burst,
    // 44 outstanding <= vmcnt capacity 63), then accumulate rows r0-5..r0+4 ----
#pragma unroll 1
    for (int i = 0; i < 11; ++i) dma_row(i, r0 - RAD + i);
#pragma unroll 1
    for (int i = 0; i < 10; ++i) {
        int ri = r0 - RAD + i;
        accum_add(&ring[i][0], ri >= 0 ? 1.0f : 0.0f);
    }
    // invariant entering step r: V = sum rows [r-5, r+4]; ring holds all
    // rows <= r+5; the DMA for row r+5 is >= 1 iteration old.

    const float inv121 = 1.0f / 121.0f;
    float loss = 0.0f;
    int sAdd = 10, sSub = 12, sPre = 11;
    const int subLo = (r0 > 0) ? (r0 - RAD) : 0;   // lowest row ever added

#pragma unroll 1
    for (int r = r0; r < r0 + SH; ++r) {
        // add row r+5 from ring (implicit vmcnt wait sees 1-iter-old DMA)
        accum_add(&ring[sAdd][0], (r + RAD < IMG_H) ? 1.0f : 0.0f);

        // sub row r-6 from ring; wave-uniform gate also keeps us from ever
        // reading the 2 uninitialized slots at the band start
        int rs = r - RAD - 1;
        if (rs >= subLo) accum_sub(&ring[sSub][0]);

        // prefetch row r+6 into the slot of dead row r-7; issued AFTER the
        // accum ds_reads so the next iteration's vmcnt drain is ~free, and
        // its latency hides under hsum+SSIM below
        if (r < r0 + SH - 1) dma_row(sPre, r + RAD + 1);

        float Sx[8], Sy[8], Sss[8], Sxy[8];
        hsum(Vx,  Sx);
        hsum(Vy,  Sy);
        hsum(Vss, Sss);
        hsum(Vxy, Sxy);

#pragma unroll
        for (int j = 0; j < 8; ++j) {
            float mx  = Sx[j] * inv121;
            float my  = Sy[j] * inv121;
            float mx2 = mx * mx;
            float my2 = my * my;
            float mxy = mx * my;
            float vs  = Sss[j] * inv121 - mx2 - my2;   // sigma_x2 + sigma_y2
            float vxy = Sxy[j] * inv121 - mxy;
            float num = (2.0f * mxy + C1_SSIM) * (2.0f * vxy + C2_SSIM);
            float den = (mx2 + my2 + C1_SSIM) * (vs + C2_SSIM);
            loss += __fdividef(num, den);
        }

        if (++sAdd == NSLOT) sAdd = 0;
        if (++sSub == NSLOT) sSub = 0;
        if (++sPre == NSLOT) sPre = 0;
    }

    // single-wave shfl reduction -> one store per block
#pragma unroll
    for (int off = 32; off > 0; off >>= 1)
        loss += __shfl_down(loss, off, 64);
    if (tx == 0)
        part[blockIdx.x] = loss;
}

// single-block finisher: reduce 512 partials (2 KB) and write the loss
__global__ __launch_bounds__(256) void ssim_reduce(const float* __restrict__ part,
                                                   float* __restrict__ out)
{
    const int t  = threadIdx.x;
    const int tx = t & 63;
    float s = part[t] + part[t + 256];
#pragma unroll
    for (int off = 32; off > 0; off >>= 1)
        s += __shfl_down(s, off, 64);
    __shared__ float ws[4];
    if (tx == 0) ws[t >> 6] = s;
    __syncthreads();
    if (t == 0) {
        float total = (ws[0] + ws[1]) + (ws[2] + ws[3]);
        out[0] = 1.0f - total * (1.0f / ((float)N_IMG * IMG_H * IMG_W));
    }
}

extern "C" void kernel_launch(void* const* d_in, const int* in_sizes, int n_in,
                              void* d_out, int out_size, void* d_ws, size_t ws_size,
                              hipStream_t stream) {
    const float* x = (const float*)d_in[0];
    const float* y = (const float*)d_in[1];
    // d_in[2] is the uniform 11x11/121 kernel; its value is compile-time known.
    float* part = (float*)d_ws;            // 512 floats, all written each call

    ssim_fused<<<NBLOCKS, 64, 0, stream>>>(x, y, part);
    ssim_reduce<<<1, 256, 0, stream>>>(part, (float*)d_out);
}

// Round 7
// 166.423 us; speedup vs baseline: 1.1573x; 1.1573x over previous
//
#include <hip/hip_runtime.h>
#include <stdint.h>

// SSIM loss — fused separable box filter. R12: stride-2 row-interleaved
// SHARED ring. Corners measured: R8 (8 waves/CU, 2.69x traffic) 74us;
// R10 (16, 3.38x) 85us; R11 (2, 1.17x) 92us, VALU 22% (0.5 waves/SIMD,
// serial-chain starved). Need low traffic AND >=4 waves/CU at once.
//
// Design: block = 2 waves sharing ONE 16-slot full-row LDS ring (64KB).
// Wave w outputs rows q = r0 + 2i + w (i=0..31) over a 64-row band.
// Per step each wave: add rows q+4,q+5; sub rows q-7,q-6 (from ring —
// every input row DMA'd exactly once per block); prefetch row q+7 into the
// slot of dead row q-9; ONE __syncthreads per step. The compiler's
// vmcnt(0)-drain-before-s_barrier is the cross-wave publication: wave w's
// DMA issued at step i is complete at the end-of-step barrier, so the other
// wave's read at step i+1 is safe. DMA targets are only slots whose last
// reader finished before the previous barrier (verified row/slot algebra:
// slot(R) = (R - r0 + 7) & 15; prefetch slot (2i+14+wv) holds dead row
// r0+2i-9+wv, last read at step i-1).
//
// Traffic: 512 blocks x 78 rows x 4KB = 160MB issued (1.22x minimum, vs
// R8's 2.69x). Waves: 512 x 2 = 4/CU (2 blocks/CU by 64KB LDS) = 1/SIMD,
// 2x R11. Per-output VALU +17% (2 add + 2 sub per output row vs 1+1).
// SSIM evaluated on raw window sums (x121 scale folded into constants:
// ratio is scale-invariant) — saves ~32 inst/step.
// Horizontal 11-col window: 5-float halo per side via __shfl (unchanged).

#define IMG_H 512
#define IMG_W 512
#define N_IMG 64
#define RAD   5
#define BAND  64                   // rows per block
#define NBANDG 8
#define NBLOCKS (N_IMG * NBANDG)   // 512
#define NSLOT 16

// constants pre-scaled by 121^2 (s=121): C1*s^2, C2*s^2, 2*s, s
#define C1S2 1.4641f
#define C2S2 13.1769f

#define SLOT_BYTES 4096            // x row (2048 B) + y row (2048 B)

typedef __attribute__((address_space(3))) uint32_t lds_u32_t;
typedef const __attribute__((address_space(1))) uint32_t glb_u32_t;

__device__ __forceinline__ void dma16(void* lds, const void* g) {
    // 64 lanes x 16 B: LDS dest = wave-uniform base + lane*16 (m104/m108)
    __builtin_amdgcn_global_load_lds((glb_u32_t*)g, (lds_u32_t*)lds, 16, 0, 0);
}

__global__ __launch_bounds__(128) void ssim_fused(const float* __restrict__ x,
                                                  const float* __restrict__ y,
                                                  float* __restrict__ part)
{
    __shared__ __align__(16) char ring[NSLOT][SLOT_BYTES];   // 64 KB exactly

    const int tx = threadIdx.x & 63;
    const int wv = threadIdx.x >> 6;            // wave id 0/1

    // XCD-aware bijective swizzle (512%8==0): XCD k owns images [8k,8k+8).
    const int wid = (blockIdx.x & 7) * (NBLOCKS / 8) + (blockIdx.x >> 3);
    const int img = wid >> 3;                   // / NBANDG
    const int bg  = wid & (NBANDG - 1);
    const int r0  = bg * BAND;
    const int q0  = r0 + wv;                    // this wave's first output row

    const float* __restrict__ xi = x + (size_t)img * (IMG_H * IMG_W);
    const float* __restrict__ yi = y + (size_t)img * (IMG_H * IMG_W);

    // DMA one (x,y) row pair into ring slot. Clamped rows load valid data;
    // their contribution is zeroed (f=0) at accumulate time.
    auto dma_row = [&](int slot, int ri) {
        int rc = ri < 0 ? 0 : (ri > IMG_H - 1 ? IMG_H - 1 : ri);
        char* s = &ring[slot][0];
        const char* xg = (const char*)(xi + (size_t)rc * IMG_W) + tx * 16;
        const char* yg = (const char*)(yi + (size_t)rc * IMG_W) + tx * 16;
        dma16(s,        xg);
        dma16(s + 1024, xg + 1024);
        dma16(s + 2048, yg);
        dma16(s + 3072, yg + 1024);
    };

    float Vx[8], Vy[8], Vss[8], Vxy[8];
#pragma unroll
    for (int j = 0; j < 8; ++j) { Vx[j] = 0.f; Vy[j] = 0.f; Vss[j] = 0.f; Vxy[j] = 0.f; }

    // add f * (row moments) from a ring slot; f = 0/1 edge scale
    auto accum_add = [&](const char* s, float f) {
        const float4* xr = (const float4*)(s + (size_t)tx * 32);
        const float4* yr = (const float4*)(s + 2048 + (size_t)tx * 32);
        float4 x0 = xr[0], x1 = xr[1];
        float4 y0 = yr[0], y1 = yr[1];
        float xs[8] = {x0.x, x0.y, x0.z, x0.w, x1.x, x1.y, x1.z, x1.w};
        float ys[8] = {y0.x, y0.y, y0.z, y0.w, y1.x, y1.y, y1.z, y1.w};
#pragma unroll
        for (int j = 0; j < 8; ++j) {
            float fx = f * xs[j];
            float fy = f * ys[j];
            Vx[j] += fx;
            Vy[j] += fy;
            Vss[j] = fmaf(fx, xs[j], Vss[j]);
            Vss[j] = fmaf(fy, ys[j], Vss[j]);
            Vxy[j] = fmaf(fx, ys[j], Vxy[j]);
        }
    };

    // subtract row moments (only ever called for rows added with f=1)
    auto accum_sub = [&](const char* s) {
        const float4* xr = (const float4*)(s + (size_t)tx * 32);
        const float4* yr = (const float4*)(s + 2048 + (size_t)tx * 32);
        float4 x0 = xr[0], x1 = xr[1];
        float4 y0 = yr[0], y1 = yr[1];
        float xs[8] = {x0.x, x0.y, x0.z, x0.w, x1.x, x1.y, x1.z, x1.w};
        float ys[8] = {y0.x, y0.y, y0.z, y0.w, y1.x, y1.y, y1.z, y1.w};
#pragma unroll
        for (int j = 0; j < 8; ++j) {
            Vx[j]  -= xs[j];
            Vy[j]  -= ys[j];
            Vss[j] = fmaf(-xs[j], xs[j], Vss[j]);
            Vss[j] = fmaf(-ys[j], ys[j], Vss[j]);
            Vxy[j] = fmaf(-xs[j], ys[j], Vxy[j]);
        }
    };

    // 11-tap sliding horizontal sums; halo via lane+-1 shuffles
    auto hsum = [&](const float (&V)[8], float (&S)[8]) {
        float w[18];
#pragma unroll
        for (int k = 0; k < 5; ++k) {
            float l = __shfl_up(V[3 + k], 1, 64);
            w[k] = (tx == 0) ? 0.f : l;
        }
#pragma unroll
        for (int j = 0; j < 8; ++j) w[5 + j] = V[j];
#pragma unroll
        for (int k = 0; k < 5; ++k) {
            float r = __shfl_down(V[k], 1, 64);
            w[13 + k] = (tx == 63) ? 0.f : r;
        }
        float s = 0.f;
#pragma unroll
        for (int t = 0; t < 11; ++t) s += w[t];
        S[0] = s;
#pragma unroll
        for (int j = 1; j < 8; ++j) { s += w[j + 10] - w[j - 1]; S[j] = s; }
    };

    // ---- warm-up: fill slots 0..13 with rows r0-7 .. r0+6 (waves split by
    // parity, 28 DMAs each <= vmcnt cap); barrier publishes; then each wave
    // accumulates its initial window V = rows q0-7 .. q0+3 ----
#pragma unroll 1
    for (int k = wv; k < 14; k += 2) dma_row(k, r0 - 7 + k);
    __syncthreads();
#pragma unroll 1
    for (int t = 0; t < 11; ++t) {
        int row = q0 - 7 + t;                    // slot = wv + t
        accum_add(&ring[wv + t][0], row >= 0 ? 1.0f : 0.0f);
    }

    float loss = 0.0f;
    int sa = wv + 11;                            // slot of row q+4 at i=0
    int ss = wv;                                 // slot of row q-7 at i=0
    int sp = wv + 14;                            // prefetch slot at i=0

#pragma unroll 1
    for (int i = 0; i < BAND / 2; ++i) {
        const int q = q0 + 2 * i;

        // adds: rows q+4, q+5 (DMA'd >=1 step ago, published by barrier)
        accum_add(&ring[sa][0],            (q + 4 < IMG_H) ? 1.0f : 0.0f);
        accum_add(&ring[(sa + 1) & 15][0], (q + 5 < IMG_H) ? 1.0f : 0.0f);

        // subs: rows q-7, q-6 (gated: only rows really added with f=1)
        if (q - 7 >= 0) accum_sub(&ring[ss][0]);
        if (q - 6 >= 0) accum_sub(&ring[(ss + 1) & 15][0]);

        // prefetch row q+7 into slot of dead row q-9 (issued AFTER the
        // accum ds_reads so no conservative vmcnt wait lands on them; its
        // latency hides under hsum+SSIM; drained at the end-of-step barrier)
        if (i < BAND / 2 - 1) dma_row(sp & 15, q + 7);

        float Sx[8], Sy[8], Sss[8], Sxy[8];
        hsum(Vx,  Sx);
        hsum(Vy,  Sy);
        hsum(Vss, Sss);
        hsum(Vxy, Sxy);

        // SSIM on raw sums: all /121 factors cancel in the ratio;
        // constants pre-scaled by 121^2.
#pragma unroll
        for (int j = 0; j < 8; ++j) {
            float A  = Sx[j] * Sy[j];
            float B  = fmaf(Sx[j], Sx[j], Sy[j] * Sy[j]);
            float n1 = fmaf(A, 2.0f, C1S2);
            float n2 = fmaf(Sxy[j], 242.0f, fmaf(A, -2.0f, C2S2));
            float d1 = B + C1S2;
            float d2 = fmaf(Sss[j], 121.0f, C2S2 - B);
            loss += __fdividef(n1 * n2, d1 * d2);
        }

        sa = (sa + 2) & 15;
        ss = (ss + 2) & 15;
        sp = (sp + 2) & 15;

        __syncthreads();   // drain own DMA (publishes to sibling) + sync
    }

    // reduction: per-wave shfl-reduce -> 2 floats in dead ring -> one store
#pragma unroll
    for (int off = 32; off > 0; off >>= 1)
        loss += __shfl_down(loss, off, 64);

    float* pr = reinterpret_cast<float*>(&ring[0][0]);
    if (tx == 0) pr[wv] = loss;                  // ring dead after last barrier
    __syncthreads();
    if (threadIdx.x == 0)
        part[blockIdx.x] = pr[0] + pr[1];
}

// single-block finisher: reduce 512 partials (2 KB) and write the loss
__global__ __launch_bounds__(256) void ssim_reduce(const float* __restrict__ part,
                                                   float* __restrict__ out)
{
    const int t  = threadIdx.x;
    const int tx = t & 63;
    float s = part[t] + part[t + 256];
#pragma unroll
    for (int off = 32; off > 0; off >>= 1)
        s += __shfl_down(s, off, 64);
    __shared__ float ws[4];
    if (tx == 0) ws[t >> 6] = s;
    __syncthreads();
    if (t == 0) {
        float total = (ws[0] + ws[1]) + (ws[2] + ws[3]);
        out[0] = 1.0f - total * (1.0f / ((float)N_IMG * IMG_H * IMG_W));
    }
}

extern "C" void kernel_launch(void* const* d_in, const int* in_sizes, int n_in,
                              void* d_out, int out_size, void* d_ws, size_t ws_size,
                              hipStream_t stream) {
    const float* x = (const float*)d_in[0];
    const float* y = (const float*)d_in[1];
    // d_in[2] is the uniform 11x11/121 kernel; its value is compile-time known.
    float* part = (float*)d_ws;            // 512 floats, all written each call

    ssim_fused<<<NBLOCKS, 128, 0, stream>>>(x, y, part);
    ssim_reduce<<<1, 256, 0, stream>>>(part, (float*)d_out);
}